// Round 1
// baseline (160.749 us; speedup 1.0000x reference)
//
#include <hip/hip_runtime.h>
#include <hip/hip_bf16.h>
#include <math.h>

// FluxHead: B=4, T=4096, D_MODEL=1024, HEAD_DIM=128, STRIDE=4, Tk=1024, CAUSAL
// Key simplifications (exact math):
//  - spectral gate adds a per-(b,q) scalar to logits -> softmax-invariant -> skipped
//  - reverse branch == unmasked forward attention, output reversed over q
//  - pooling commutes with K/V projection: pool x first (4x fewer proj FLOPs)
//  - log2e/SCALE folded into Wq -> softmax in exp2 units

#define B_ 4
#define T_ 4096
#define DM_ 1024
#define HD_ 128
#define TK_ 1024

typedef __attribute__((ext_vector_type(8))) short bf16x8;
typedef __attribute__((ext_vector_type(4))) float f32x4;

__device__ inline short f2bf(float f) {
  unsigned u = __builtin_bit_cast(unsigned, f);
  u = (u + 0x7FFFu + ((u >> 16) & 1u)) >> 16;
  return (short)u;
}

__device__ inline f32x4 mfma16(bf16x8 a, bf16x8 b, f32x4 c) {
  return __builtin_amdgcn_mfma_f32_16x16x32_bf16(a, b, c, 0, 0, 0);
}

// ---- pool: xp[b][t'][:] = mean of 4 consecutive x rows (f32) ----
__global__ __launch_bounds__(256) void pool_kernel(const float* __restrict__ x,
                                                   float* __restrict__ xp) {
  int i = blockIdx.x * 256 + threadIdx.x;      // over 4096 pooled rows * 256 float4
  int pr = i >> 8, c4 = i & 255;
  const float4* xr = (const float4*)x + ((size_t)pr * 4) * 256 + c4;
  float4 a = xr[0], b = xr[256], c = xr[512], d = xr[768];
  float4 r;
  r.x = (a.x + b.x + c.x + d.x) * 0.25f;
  r.y = (a.y + b.y + c.y + d.y) * 0.25f;
  r.z = (a.z + b.z + c.z + d.z) * 0.25f;
  r.w = (a.w + b.w + c.w + d.w) * 0.25f;
  ((float4*)xp)[i] = r;
}

// ---- rope table: cos/sin[t][d], t<4096, d<64 ----
__global__ __launch_bounds__(256) void rope_kernel(float* __restrict__ cosT,
                                                   float* __restrict__ sinT) {
  int i = blockIdx.x * 256 + threadIdx.x;      // 262144
  int t = i >> 6, d = i & 63;
  float theta = powf(10000.f, -(float)d * (1.f / 64.f));
  float fr = (float)t * theta;
  cosT[i] = cosf(fr);
  sinT[i] = sinf(fr);
}

// ---- W^T concat bf16: WT[m][n][k], m=0 Wq (scaled), 1 Wk, 2 Wv ----
__global__ __launch_bounds__(256) void wtprep_kernel(const float* __restrict__ Wq,
                                                     const float* __restrict__ Wk,
                                                     const float* __restrict__ Wv,
                                                     short* __restrict__ WT) {
  int i = blockIdx.x * 256 + threadIdx.x;      // 3*128*1024
  int m = i >> 17;
  int n = (i >> 10) & 127;
  int k = i & 1023;
  const float* W = (m == 0) ? Wq : ((m == 1) ? Wk : Wv);
  float v = W[(size_t)k * 128 + n];
  if (m == 0) v *= 0.12751741656f;  // log2(e)/sqrt(128)
  WT[i] = f2bf(v);
}

// ---- projection GEMM: C[M x 128] = A[M x 1024](f32) @ W, W given as WT[n][k] bf16
// MODE 0: out=Q_bf (rope, positions q)    MODE 1: out=K_bf (rope, positions k)
// MODE 2: out=V^T bf16 [b][d][k]
template <int MODE>
__global__ __launch_bounds__(256) void gemm_proj(const float* __restrict__ A,
                                                 const short* __restrict__ WT,
                                                 const float* __restrict__ cosT,
                                                 const float* __restrict__ sinT,
                                                 short* __restrict__ Out) {
  __shared__ __align__(16) char Al[8192];    // 64 rows x 64k bf16, row pitch 128B, XOR swz
  __shared__ __align__(16) char Wl[16384];   // 128 n x 64k bf16, row pitch 128B, XOR swz
  const int tid = threadIdx.x;
  const int w = tid >> 6, g = (tid >> 4) & 3, c = tid & 15;
  const int m0 = blockIdx.x * 64;
  const int swc = (c & 7) << 4;
  f32x4 acc[8];
#pragma unroll
  for (int n = 0; n < 8; n++) acc[n] = (f32x4){0.f, 0.f, 0.f, 0.f};

  for (int ki = 0; ki < 16; ki++) {
    {
      int row = tid >> 2, part = tid & 3;
      const float4* ap = (const float4*)(A + ((size_t)(m0 + row)) * 1024 + ki * 64 + part * 16);
      float4 f0 = ap[0], f1 = ap[1], f2 = ap[2], f3 = ap[3];
      bf16x8 s0, s1;
      s0[0] = f2bf(f0.x); s0[1] = f2bf(f0.y); s0[2] = f2bf(f0.z); s0[3] = f2bf(f0.w);
      s0[4] = f2bf(f1.x); s0[5] = f2bf(f1.y); s0[6] = f2bf(f1.z); s0[7] = f2bf(f1.w);
      s1[0] = f2bf(f2.x); s1[1] = f2bf(f2.y); s1[2] = f2bf(f2.z); s1[3] = f2bf(f2.w);
      s1[4] = f2bf(f3.x); s1[5] = f2bf(f3.y); s1[6] = f2bf(f3.z); s1[7] = f2bf(f3.w);
      int sw = (row & 7) << 4;
      char* base = Al + row * 128;
      *(bf16x8*)(base + ((part * 32) ^ sw)) = s0;
      *(bf16x8*)(base + ((part * 32 + 16) ^ sw)) = s1;

      int wrow = tid >> 1, half = tid & 1;
      const bf16x8* wp = (const bf16x8*)(WT + (size_t)wrow * 1024 + ki * 64 + half * 32);
      char* wbase = Wl + wrow * 128;
      int sww = (wrow & 7) << 4;
#pragma unroll
      for (int i2 = 0; i2 < 4; i2++)
        *(bf16x8*)(wbase + ((half * 64 + i2 * 16) ^ sww)) = wp[i2];
    }
    __syncthreads();
    bf16x8 af0 = *(const bf16x8*)(Al + (w * 16 + c) * 128 + ((16 * g) ^ swc));
    bf16x8 af1 = *(const bf16x8*)(Al + (w * 16 + c) * 128 + ((64 + 16 * g) ^ swc));
#pragma unroll
    for (int n0 = 0; n0 < 8; n0++) {
      int row = n0 * 16 + c;
      bf16x8 b0 = *(const bf16x8*)(Wl + row * 128 + ((16 * g) ^ swc));
      bf16x8 b1 = *(const bf16x8*)(Wl + row * 128 + ((64 + 16 * g) ^ swc));
      acc[n0] = mfma16(af0, b0, acc[n0]);
      acc[n0] = mfma16(af1, b1, acc[n0]);
    }
    __syncthreads();
  }
  // epilogue: lane holds out[m = m0+w*16+4g+r][d = n0*16+c]
  if (MODE < 2) {
#pragma unroll
    for (int r = 0; r < 4; r++) {
      int m = m0 + w * 16 + 4 * g + r;
      int t = (MODE == 0) ? (m & 4095) : (m & 1023);
#pragma unroll
      for (int n0 = 0; n0 < 4; n0++) {
        int dm = n0 * 16 + c;
        float co = cosT[t * 64 + dm], si = sinT[t * 64 + dm];
        float lo = acc[n0][r], hi = acc[n0 + 4][r];
        Out[(size_t)m * 128 + dm] = f2bf(lo * co - hi * si);
        Out[(size_t)m * 128 + dm + 64] = f2bf(hi * co + lo * si);
      }
    }
  } else {
#pragma unroll
    for (int r = 0; r < 4; r++) {
      int m = m0 + w * 16 + 4 * g + r;
      int bb = m >> 10, k = m & 1023;
#pragma unroll
      for (int n0 = 0; n0 < 8; n0++)
        Out[((size_t)(bb * 128) + n0 * 16 + c) * 1024 + k] = f2bf(acc[n0][r]);
    }
  }
}

// ---- fused two-branch flash attention ----
// block = 128 thr (2 waves), 32 queries/block, wave = 16 queries
__global__ __launch_bounds__(128) void attn_kernel(const short* __restrict__ Qb,
                                                   const short* __restrict__ Kb,
                                                   const short* __restrict__ VT,
                                                   const float* __restrict__ alphap,
                                                   float* __restrict__ outc,
                                                   float* __restrict__ outu) {
  __shared__ __align__(16) char Kl[16384];   // 64 keys x 128d bf16, pitch 256B, swz
  __shared__ __align__(16) char Vl[16384];   // 128 d x 64 keys bf16, pitch 128B, swz
  __shared__ __align__(16) char Pl2[4608];   // per wave 16q x 64k bf16, pitch 144B
  const int tid = threadIdx.x;
  const int w = tid >> 6, g = (tid >> 4) & 3, c = tid & 15;
  char* Pl = Pl2 + w * 2304;
  const int blk = blockIdx.x;
  const int b = blk >> 7;
  const int q0 = (blk & 127) * 32 + w * 16;
  const int swc = (c & 7) << 4;
  const int tile_b = q0 >> 8;  // boundary key-tile for this wave

  bf16x8 qf[4];
  {
    const short* qr = Qb + ((size_t)b * T_ + q0 + c) * 128;
#pragma unroll
    for (int kc = 0; kc < 4; kc++) qf[kc] = *(const bf16x8*)(qr + kc * 32 + 8 * g);
  }
  f32x4 accu[8], accc[8];
#pragma unroll
  for (int n = 0; n < 8; n++) { accu[n] = (f32x4){0,0,0,0}; accc[n] = (f32x4){0,0,0,0}; }
  float m[4], lu[4], lc[4];
#pragma unroll
  for (int r = 0; r < 4; r++) { m[r] = -1e30f; lu[r] = 0.f; lc[r] = 0.f; }

  for (int t = 0; t < 16; t++) {
    {  // stage K tile + V^T tile (both waves cooperate)
      int row = tid >> 1, half = tid & 1;
      const bf16x8* src = (const bf16x8*)(Kb + ((size_t)b * TK_ + t * 64 + row) * 128 + half * 64);
      char* dst = Kl + row * 256;
      int sw = (row & 7) << 4;
#pragma unroll
      for (int i2 = 0; i2 < 8; i2++)
        *(bf16x8*)(dst + ((half * 128 + i2 * 16) ^ sw)) = src[i2];
      const bf16x8* vs = (const bf16x8*)(VT + ((size_t)b * 128 + tid) * 1024 + t * 64);
      char* vd = Vl + tid * 128;
      int sw2 = (tid & 7) << 4;
#pragma unroll
      for (int i2 = 0; i2 < 8; i2++)
        *(bf16x8*)(vd + ((i2 * 16) ^ sw2)) = vs[i2];
    }
    __syncthreads();
    // S tile: 16q x 64 keys (log2-units, scale prefolded into Wq)
    f32x4 s[4];
#pragma unroll
    for (int n = 0; n < 4; n++) s[n] = (f32x4){0,0,0,0};
#pragma unroll
    for (int kc = 0; kc < 4; kc++) {
#pragma unroll
      for (int n = 0; n < 4; n++) {
        int row = n * 16 + c;
        bf16x8 kf = *(const bf16x8*)(Kl + row * 256 + ((kc * 64 + 16 * g) ^ swc));
        s[n] = mfma16(qf[kc], kf, s[n]);
      }
    }
    // online softmax, shared running max for both branches
    float sc[4], rs[4];
#pragma unroll
    for (int r = 0; r < 4; r++) {
      float tm = fmaxf(fmaxf(s[0][r], s[1][r]), fmaxf(s[2][r], s[3][r]));
      tm = fmaxf(tm, __shfl_xor(tm, 1));
      tm = fmaxf(tm, __shfl_xor(tm, 2));
      tm = fmaxf(tm, __shfl_xor(tm, 4));
      tm = fmaxf(tm, __shfl_xor(tm, 8));
      float mn = fmaxf(m[r], tm);
      sc[r] = __builtin_amdgcn_exp2f(m[r] - mn);
      m[r] = mn;
      lu[r] *= sc[r]; lc[r] *= sc[r];
    }
    f32x4 p[4];
#pragma unroll
    for (int n = 0; n < 4; n++)
#pragma unroll
      for (int r = 0; r < 4; r++) p[n][r] = __builtin_amdgcn_exp2f(s[n][r] - m[r]);
#pragma unroll
    for (int r = 0; r < 4; r++) {
      float sum = p[0][r] + p[1][r] + p[2][r] + p[3][r];
      sum += __shfl_xor(sum, 1); sum += __shfl_xor(sum, 2);
      sum += __shfl_xor(sum, 4); sum += __shfl_xor(sum, 8);
      rs[r] = sum; lu[r] += sum;
    }
    f32x4 scv = {sc[0], sc[1], sc[2], sc[3]};
#pragma unroll
    for (int n0 = 0; n0 < 8; n0++) { accu[n0] *= scv; accc[n0] *= scv; }
    // pack P (C-layout -> A-layout via LDS round-trip)
#pragma unroll
    for (int n = 0; n < 4; n++)
#pragma unroll
      for (int r = 0; r < 4; r++)
        *(short*)(Pl + (4 * g + r) * 144 + (n * 16 + c) * 2) = f2bf(p[n][r]);
    const bool do_c = (t < tile_b);
    if (do_c) {
#pragma unroll
      for (int r = 0; r < 4; r++) lc[r] += rs[r];
    }
    bf16x8 pf0 = *(const bf16x8*)(Pl + c * 144 + 16 * g);
    bf16x8 pf1 = *(const bf16x8*)(Pl + c * 144 + 64 + 16 * g);
#pragma unroll
    for (int n0 = 0; n0 < 8; n0++) {
      int row = n0 * 16 + c;
      bf16x8 v0 = *(const bf16x8*)(Vl + row * 128 + ((16 * g) ^ swc));
      bf16x8 v1 = *(const bf16x8*)(Vl + row * 128 + ((64 + 16 * g) ^ swc));
      accu[n0] = mfma16(pf0, v0, accu[n0]);
      accu[n0] = mfma16(pf1, v1, accu[n0]);
      if (do_c) {
        accc[n0] = mfma16(pf0, v0, accc[n0]);
        accc[n0] = mfma16(pf1, v1, accc[n0]);
      }
    }
    if (t == tile_b) {  // boundary tile: masked contribution to causal branch
#pragma unroll
      for (int r = 0; r < 4; r++) {
        int qq = q0 + 4 * g + r;
        int klim = (qq >> 2) - t * 64;  // allowed local key <= klim
        float sum = 0.f;
#pragma unroll
        for (int n = 0; n < 4; n++) {
          int key = n * 16 + c;
          float pm = (key <= klim) ? p[n][r] : 0.f;
          p[n][r] = pm; sum += pm;
        }
        sum += __shfl_xor(sum, 1); sum += __shfl_xor(sum, 2);
        sum += __shfl_xor(sum, 4); sum += __shfl_xor(sum, 8);
        lc[r] += sum;
      }
#pragma unroll
      for (int n = 0; n < 4; n++)
#pragma unroll
        for (int r = 0; r < 4; r++)
          *(short*)(Pl + (4 * g + r) * 144 + (n * 16 + c) * 2) = f2bf(p[n][r]);
      bf16x8 mf0 = *(const bf16x8*)(Pl + c * 144 + 16 * g);
      bf16x8 mf1 = *(const bf16x8*)(Pl + c * 144 + 64 + 16 * g);
#pragma unroll
      for (int n0 = 0; n0 < 8; n0++) {
        int row = n0 * 16 + c;
        bf16x8 v0 = *(const bf16x8*)(Vl + row * 128 + ((16 * g) ^ swc));
        bf16x8 v1 = *(const bf16x8*)(Vl + row * 128 + ((64 + 16 * g) ^ swc));
        accc[n0] = mfma16(mf0, v0, accc[n0]);
        accc[n0] = mfma16(mf1, v1, accc[n0]);
      }
    }
    __syncthreads();
  }
  float fa = alphap[0];
  float alpha = 1.f / (1.f + expf(-fa));
#pragma unroll
  for (int n0 = 0; n0 < 8; n0++) {
#pragma unroll
    for (int r = 0; r < 4; r++) {
      size_t o = ((size_t)b * T_ + q0 + 4 * g + r) * 128 + n0 * 16 + c;
      outc[o] = alpha * accc[n0][r] / lc[r];
      outu[o] = accu[n0][r] / lu[r];
    }
  }
}

// ---- combine: out[b][q] += (1-alpha) * u[b][T-1-q] ----
__global__ __launch_bounds__(256) void combine_kernel(float* __restrict__ out,
                                                      const float* __restrict__ ub,
                                                      const float* __restrict__ alphap) {
  int i = blockIdx.x * 256 + threadIdx.x;  // 524288 float4
  float fa = alphap[0];
  float onema = 1.f - 1.f / (1.f + expf(-fa));
  int row = i >> 5, col = i & 31;
  int b = row >> 12, q = row & 4095;
  const float4* u = (const float4*)ub + ((size_t)(b << 12) + (4095 - q)) * 32 + col;
  float4 uu = *u;
  float4* o = (float4*)out + i;
  float4 oo = *o;
  oo.x += onema * uu.x; oo.y += onema * uu.y;
  oo.z += onema * uu.z; oo.w += onema * uu.w;
  *o = oo;
}

extern "C" void kernel_launch(void* const* d_in, const int* in_sizes, int n_in,
                              void* d_out, int out_size, void* d_ws, size_t ws_size,
                              hipStream_t stream) {
  const float* x = (const float*)d_in[0];
  const float* Wq = (const float*)d_in[1];
  const float* Wk = (const float*)d_in[2];
  const float* Wv = (const float*)d_in[3];
  const float* falpha = (const float*)d_in[9];
  char* ws = (char*)d_ws;
  float* xp = (float*)ws;                          // 16 MB  pooled x (f32)
  float* cosT = (float*)(ws + 16777216);           // 1 MB
  float* sinT = (float*)(ws + 17825792);           // 1 MB
  short* WT = (short*)(ws + 18874368);             // 768 KB [3][128][1024] bf16
  short* Qb = (short*)(ws + 19660800);             // 4 MB   roped+scaled Q bf16
  short* Kb = (short*)(ws + 23855104);             // 1 MB   roped K_pool bf16
  short* VT = (short*)(ws + 24903680);             // 1 MB   V_pool^T bf16 [b][d][k]
  float* ub = (float*)(ws + 25952256);             // 8 MB   unmasked branch out

  pool_kernel<<<4096, 256, 0, stream>>>(x, xp);
  rope_kernel<<<1024, 256, 0, stream>>>(cosT, sinT);
  wtprep_kernel<<<1536, 256, 0, stream>>>(Wq, Wk, Wv, WT);
  gemm_proj<0><<<256, 256, 0, stream>>>(x, WT, cosT, sinT, Qb);
  gemm_proj<1><<<64, 256, 0, stream>>>(xp, WT + 131072, cosT, sinT, Kb);
  gemm_proj<2><<<64, 256, 0, stream>>>(xp, WT + 262144, cosT, sinT, VT);
  attn_kernel<<<512, 128, 0, stream>>>(Qb, Kb, VT, falpha, (float*)d_out, ub);
  combine_kernel<<<2048, 256, 0, stream>>>((float*)d_out, ub, falpha);
}

// Round 2
// 140.234 us; speedup vs baseline: 1.1463x; 1.1463x over previous
//
#include <hip/hip_runtime.h>
#include <hip/hip_bf16.h>
#include <math.h>

// FluxHead: B=4, T=4096, D_MODEL=1024, HEAD_DIM=128, STRIDE=4, Tk=1024, CAUSAL
// Exact-math simplifications:
//  - spectral gate adds a per-(b,q) scalar to logits -> softmax-invariant -> skipped
//  - reverse branch == unmasked forward attention, output reversed over q
//  - pooling commutes with K/V projection -> pool in GEMM epilogue (lane-local)
//  - log2e/SCALE folded into Wq -> softmax in exp2 units

#define B_ 4
#define T_ 4096
#define TK_ 1024

typedef __attribute__((ext_vector_type(8))) short bf16x8;
typedef __attribute__((ext_vector_type(4))) float f32x4;

__device__ inline short f2bf(float f) {
  unsigned u = __builtin_bit_cast(unsigned, f);
  u = (u + 0x7FFFu + ((u >> 16) & 1u)) >> 16;
  return (short)u;
}

__device__ inline f32x4 mfma16(bf16x8 a, bf16x8 b, f32x4 c) {
  return __builtin_amdgcn_mfma_f32_16x16x32_bf16(a, b, c, 0, 0, 0);
}

// ---- rope table: cos/sin[t][d], t<4096, d<64 ----
__global__ __launch_bounds__(256) void rope_kernel(float* __restrict__ cosT,
                                                   float* __restrict__ sinT) {
  int i = blockIdx.x * 256 + threadIdx.x;  // 262144
  int t = i >> 6, d = i & 63;
  float theta = powf(10000.f, -(float)d * (1.f / 64.f));
  float fr = (float)t * theta;
  cosT[i] = cosf(fr);
  sinT[i] = sinf(fr);
}

// ---- W^T concat bf16: WT[n][k], n: 0..127 Wq*scale, 128..255 Wk, 256..383 Wv ----
__global__ __launch_bounds__(256) void wtprep_kernel(const float* __restrict__ Wq,
                                                     const float* __restrict__ Wk,
                                                     const float* __restrict__ Wv,
                                                     short* __restrict__ WT) {
  int i = blockIdx.x * 256 + threadIdx.x;  // 3*128*1024
  int m = i >> 17;
  int n = (i >> 10) & 127;
  int k = i & 1023;
  const float* W = (m == 0) ? Wq : ((m == 1) ? Wk : Wv);
  float v = W[(size_t)k * 128 + n];
  if (m == 0) v *= 0.12751741656f;  // log2(e)/sqrt(128)
  WT[i] = f2bf(v);
}

// ---- fused projection GEMM: [64 rows x 1024] @ WT^T -> N=384 {Q|K|V}
// epilogue: Q roped -> Qb; K pooled(x4, lane-local)+roped -> Kb; V pooled -> VT
__global__ __launch_bounds__(256) void gemm_fused(const float* __restrict__ A,
                                                  const short* __restrict__ WT,
                                                  const float* __restrict__ cosT,
                                                  const float* __restrict__ sinT,
                                                  short* __restrict__ Qb,
                                                  short* __restrict__ Kb,
                                                  short* __restrict__ VT) {
  __shared__ __align__(16) char Al[8192];    // 64 rows x 64k bf16, pitch 128B, XOR swz
  __shared__ __align__(16) char Wl[49152];   // 384 n x 64k bf16, pitch 128B, XOR swz
  const int tid = threadIdx.x;
  const int w = tid >> 6, g = (tid >> 4) & 3, c = tid & 15;
  const int m0 = blockIdx.x * 64;
  const int swc = (c & 7) << 4;
  f32x4 acc[24];
#pragma unroll
  for (int n = 0; n < 24; n++) acc[n] = (f32x4){0.f, 0.f, 0.f, 0.f};

  for (int ki = 0; ki < 16; ki++) {
    {
      int row = tid >> 2, part = tid & 3;
      const float4* ap = (const float4*)(A + ((size_t)(m0 + row)) * 1024 + ki * 64 + part * 16);
      float4 f0 = ap[0], f1 = ap[1], f2 = ap[2], f3 = ap[3];
      bf16x8 s0, s1;
      s0[0] = f2bf(f0.x); s0[1] = f2bf(f0.y); s0[2] = f2bf(f0.z); s0[3] = f2bf(f0.w);
      s0[4] = f2bf(f1.x); s0[5] = f2bf(f1.y); s0[6] = f2bf(f1.z); s0[7] = f2bf(f1.w);
      s1[0] = f2bf(f2.x); s1[1] = f2bf(f2.y); s1[2] = f2bf(f2.z); s1[3] = f2bf(f2.w);
      s1[4] = f2bf(f3.x); s1[5] = f2bf(f3.y); s1[6] = f2bf(f3.z); s1[7] = f2bf(f3.w);
      int sw = (row & 7) << 4;
      char* base = Al + row * 128;
      *(bf16x8*)(base + ((part * 32) ^ sw)) = s0;
      *(bf16x8*)(base + ((part * 32 + 16) ^ sw)) = s1;
#pragma unroll
      for (int j = 0; j < 3; j++) {
        int wrow = (tid >> 1) + 128 * j, half = tid & 1;
        const bf16x8* wp = (const bf16x8*)(WT + (size_t)wrow * 1024 + ki * 64 + half * 32);
        char* wbase = Wl + wrow * 128;
        int sww = (wrow & 7) << 4;
#pragma unroll
        for (int i2 = 0; i2 < 4; i2++)
          *(bf16x8*)(wbase + ((half * 64 + i2 * 16) ^ sww)) = wp[i2];
      }
    }
    __syncthreads();
    bf16x8 af0 = *(const bf16x8*)(Al + (w * 16 + c) * 128 + ((16 * g) ^ swc));
    bf16x8 af1 = *(const bf16x8*)(Al + (w * 16 + c) * 128 + ((64 + 16 * g) ^ swc));
#pragma unroll
    for (int n0 = 0; n0 < 24; n0++) {
      int row = n0 * 16 + c;
      bf16x8 b0 = *(const bf16x8*)(Wl + row * 128 + ((16 * g) ^ swc));
      bf16x8 b1 = *(const bf16x8*)(Wl + row * 128 + ((64 + 16 * g) ^ swc));
      acc[n0] = mfma16(af0, b0, acc[n0]);
      acc[n0] = mfma16(af1, b1, acc[n0]);
    }
    __syncthreads();
  }
  // ---- epilogue ----
  // Q (cols 0..127): rope at position q = m & 4095
#pragma unroll
  for (int r = 0; r < 4; r++) {
    int m = m0 + w * 16 + 4 * g + r;
    int t = m & 4095;
#pragma unroll
    for (int n0 = 0; n0 < 4; n0++) {
      int dm = n0 * 16 + c;
      float co = cosT[t * 64 + dm], si = sinT[t * 64 + dm];
      float lo = acc[n0][r], hi = acc[n0 + 4][r];
      Qb[(size_t)m * 128 + dm] = f2bf(lo * co - hi * si);
      Qb[(size_t)m * 128 + dm + 64] = f2bf(hi * co + lo * si);
    }
  }
  // K (cols 128..255): pool over r (lane-local), rope at kpos
  {
    int kp = m0 / 4 + w * 4 + g;        // pooled global row, 0..4095
    int bb = kp >> 10, kpos = kp & 1023;
    float kacc[8];
#pragma unroll
    for (int j = 0; j < 8; j++)
      kacc[j] = 0.25f * (acc[8 + j][0] + acc[8 + j][1] + acc[8 + j][2] + acc[8 + j][3]);
#pragma unroll
    for (int j = 0; j < 4; j++) {
      int dm = j * 16 + c;
      float co = cosT[kpos * 64 + dm], si = sinT[kpos * 64 + dm];
      float lo = kacc[j], hi = kacc[j + 4];
      Kb[(size_t)kp * 128 + dm] = f2bf(lo * co - hi * si);
      Kb[(size_t)kp * 128 + dm + 64] = f2bf(hi * co + lo * si);
    }
    // V (cols 256..383): pool, write transposed VT[b][d][k]
#pragma unroll
    for (int j = 0; j < 8; j++) {
      float vp = 0.25f * (acc[16 + j][0] + acc[16 + j][1] + acc[16 + j][2] + acc[16 + j][3]);
      int dm = j * 16 + c;
      VT[((size_t)(bb * 128 + dm)) * 1024 + kpos] = f2bf(vp);
    }
  }
}

// ---- barrier-free two-branch flash attention, 2-way K-split ----
// 1 wave per block, 16 queries, 512 keys (8 tiles of 64). K/V read direct from L2.
__global__ __launch_bounds__(64) void attn2_kernel(const short* __restrict__ Qb,
                                                   const short* __restrict__ Kb,
                                                   const short* __restrict__ VT,
                                                   float* __restrict__ accC,
                                                   float2* __restrict__ mlC,
                                                   float* __restrict__ accU,
                                                   float2* __restrict__ mlU) {
  __shared__ __align__(16) char Pl[2304];  // 16q x 64k bf16, pitch 144B (wave-local)
  const int tid = threadIdx.x;
  const int g = (tid >> 4) & 3, c = tid & 15;
  const int blk = blockIdx.x;
  const int h = blk & 1;               // key half
  const int qc = (blk >> 1) & 255;     // q chunk (16 rows)
  const int b = blk >> 9;
  const int q0 = qc * 16;
  const int tile_b = q0 >> 8;          // boundary key tile (global index)
  const int swcq = 0;
  (void)swcq;

  bf16x8 qf[4];
  {
    const short* qr = Qb + ((size_t)b * T_ + q0 + c) * 128;
#pragma unroll
    for (int kc = 0; kc < 4; kc++) qf[kc] = *(const bf16x8*)(qr + kc * 32 + 8 * g);
  }
  f32x4 accu[8], accc[8];
#pragma unroll
  for (int n = 0; n < 8; n++) { accu[n] = (f32x4){0,0,0,0}; accc[n] = (f32x4){0,0,0,0}; }
  float m[4], lu[4], lc[4];
#pragma unroll
  for (int r = 0; r < 4; r++) { m[r] = -1e30f; lu[r] = 0.f; lc[r] = 0.f; }

  for (int t = 0; t < 8; t++) {
    const int tg = h * 8 + t;
    // S tile: 16q x 64 keys (log2 units)
    f32x4 s[4];
#pragma unroll
    for (int n = 0; n < 4; n++) s[n] = (f32x4){0,0,0,0};
#pragma unroll
    for (int kc = 0; kc < 4; kc++) {
#pragma unroll
      for (int n = 0; n < 4; n++) {
        bf16x8 kf = *(const bf16x8*)(Kb + ((size_t)(b * TK_ + tg * 64 + n * 16 + c)) * 128 + kc * 32 + 8 * g);
        s[n] = mfma16(qf[kc], kf, s[n]);
      }
    }
    // online softmax (shared running max for both branches)
    float sc[4], rs[4];
#pragma unroll
    for (int r = 0; r < 4; r++) {
      float tm = fmaxf(fmaxf(s[0][r], s[1][r]), fmaxf(s[2][r], s[3][r]));
      tm = fmaxf(tm, __shfl_xor(tm, 1));
      tm = fmaxf(tm, __shfl_xor(tm, 2));
      tm = fmaxf(tm, __shfl_xor(tm, 4));
      tm = fmaxf(tm, __shfl_xor(tm, 8));
      float mn = fmaxf(m[r], tm);
      sc[r] = __builtin_amdgcn_exp2f(m[r] - mn);
      m[r] = mn;
      lu[r] *= sc[r]; lc[r] *= sc[r];
    }
    f32x4 p[4];
#pragma unroll
    for (int n = 0; n < 4; n++)
#pragma unroll
      for (int r = 0; r < 4; r++) p[n][r] = __builtin_amdgcn_exp2f(s[n][r] - m[r]);
#pragma unroll
    for (int r = 0; r < 4; r++) {
      float sum = p[0][r] + p[1][r] + p[2][r] + p[3][r];
      sum += __shfl_xor(sum, 1); sum += __shfl_xor(sum, 2);
      sum += __shfl_xor(sum, 4); sum += __shfl_xor(sum, 8);
      rs[r] = sum; lu[r] += sum;
    }
    f32x4 scv = {sc[0], sc[1], sc[2], sc[3]};
#pragma unroll
    for (int n0 = 0; n0 < 8; n0++) { accu[n0] *= scv; accc[n0] *= scv; }
    // pack P: C-layout -> A-layout via wave-local LDS (no barrier needed)
#pragma unroll
    for (int n = 0; n < 4; n++)
#pragma unroll
      for (int r = 0; r < 4; r++)
        *(short*)(Pl + (4 * g + r) * 144 + (n * 16 + c) * 2) = f2bf(p[n][r]);
    const bool do_c = (tg < tile_b);
    if (do_c) {
#pragma unroll
      for (int r = 0; r < 4; r++) lc[r] += rs[r];
    }
    bf16x8 pf0 = *(const bf16x8*)(Pl + c * 144 + 16 * g);
    bf16x8 pf1 = *(const bf16x8*)(Pl + c * 144 + 64 + 16 * g);
#pragma unroll
    for (int n0 = 0; n0 < 8; n0++) {
      const short* vr = VT + ((size_t)(b * 128 + n0 * 16 + c)) * 1024 + tg * 64;
      bf16x8 v0 = *(const bf16x8*)(vr + 8 * g);
      bf16x8 v1 = *(const bf16x8*)(vr + 32 + 8 * g);
      accu[n0] = mfma16(pf0, v0, accu[n0]);
      accu[n0] = mfma16(pf1, v1, accu[n0]);
      if (do_c) {
        accc[n0] = mfma16(pf0, v0, accc[n0]);
        accc[n0] = mfma16(pf1, v1, accc[n0]);
      }
    }
    if (tg == tile_b) {  // boundary tile: masked contribution to causal branch
#pragma unroll
      for (int r = 0; r < 4; r++) {
        int qq = q0 + 4 * g + r;
        int klim = (qq >> 2) - tg * 64;  // allowed local key <= klim
        float sum = 0.f;
#pragma unroll
        for (int n = 0; n < 4; n++) {
          int key = n * 16 + c;
          float pm = (key <= klim) ? p[n][r] : 0.f;
          p[n][r] = pm; sum += pm;
        }
        sum += __shfl_xor(sum, 1); sum += __shfl_xor(sum, 2);
        sum += __shfl_xor(sum, 4); sum += __shfl_xor(sum, 8);
        lc[r] += sum;
      }
#pragma unroll
      for (int n = 0; n < 4; n++)
#pragma unroll
        for (int r = 0; r < 4; r++)
          *(short*)(Pl + (4 * g + r) * 144 + (n * 16 + c) * 2) = f2bf(p[n][r]);
      bf16x8 mf0 = *(const bf16x8*)(Pl + c * 144 + 16 * g);
      bf16x8 mf1 = *(const bf16x8*)(Pl + c * 144 + 64 + 16 * g);
#pragma unroll
      for (int n0 = 0; n0 < 8; n0++) {
        const short* vr = VT + ((size_t)(b * 128 + n0 * 16 + c)) * 1024 + tg * 64;
        bf16x8 v0 = *(const bf16x8*)(vr + 8 * g);
        bf16x8 v1 = *(const bf16x8*)(vr + 32 + 8 * g);
        accc[n0] = mfma16(mf0, v0, accc[n0]);
        accc[n0] = mfma16(mf1, v1, accc[n0]);
      }
    }
  }
  // write partials: acc[(b*4096+q)*2+h][128], ml[(b*4096+q)*2+h]
#pragma unroll
  for (int n0 = 0; n0 < 8; n0++) {
#pragma unroll
    for (int r = 0; r < 4; r++) {
      int q = q0 + 4 * g + r;
      size_t o = (((size_t)(b * T_ + q)) * 2 + h) * 128 + n0 * 16 + c;
      accC[o] = accc[n0][r];
      accU[o] = accu[n0][r];
    }
  }
  if (c == 0) {
#pragma unroll
    for (int r = 0; r < 4; r++) {
      int q = q0 + 4 * g + r;
      size_t o = ((size_t)(b * T_ + q)) * 2 + h;
      mlC[o] = make_float2(m[r], lc[r]);
      mlU[o] = make_float2(m[r], lu[r]);
    }
  }
}

// ---- merge halves + combine branches: out[b][q] = a*C(q) + (1-a)*U(4095-q) ----
__global__ __launch_bounds__(256) void merge_kernel(const float* __restrict__ accC,
                                                    const float2* __restrict__ mlC,
                                                    const float* __restrict__ accU,
                                                    const float2* __restrict__ mlU,
                                                    const float* __restrict__ alphap,
                                                    float* __restrict__ out) {
  int i = blockIdx.x * 256 + threadIdx.x;  // 524288 float4
  int row = i >> 5, col = i & 31;
  int b = row >> 12, q = row & 4095;
  float alpha = 1.f / (1.f + expf(-alphap[0]));
  // causal at (b,q)
  float2 c0 = mlC[(size_t)row * 2], c1 = mlC[(size_t)row * 2 + 1];
  float Mc = fmaxf(c0.x, c1.x);
  float e0 = exp2f(c0.x - Mc), e1 = exp2f(c1.x - Mc);
  float dc = c0.y * e0 + c1.y * e1;
  float wc0 = e0 / dc, wc1 = e1 / dc;
  float4 a0 = ((const float4*)accC)[(size_t)(row * 2) * 32 + col];
  float4 a1 = ((const float4*)accC)[(size_t)(row * 2 + 1) * 32 + col];
  // unmasked at (b, 4095-q)
  int rowu = (b << 12) + (4095 - q);
  float2 u0 = mlU[(size_t)rowu * 2], u1 = mlU[(size_t)rowu * 2 + 1];
  float Mu = fmaxf(u0.x, u1.x);
  float f0 = exp2f(u0.x - Mu), f1 = exp2f(u1.x - Mu);
  float du = u0.y * f0 + u1.y * f1;
  float wu0 = f0 / du, wu1 = f1 / du;
  float4 b0 = ((const float4*)accU)[(size_t)(rowu * 2) * 32 + col];
  float4 b1 = ((const float4*)accU)[(size_t)(rowu * 2 + 1) * 32 + col];
  float om = 1.f - alpha;
  float4 r;
  r.x = alpha * (wc0 * a0.x + wc1 * a1.x) + om * (wu0 * b0.x + wu1 * b1.x);
  r.y = alpha * (wc0 * a0.y + wc1 * a1.y) + om * (wu0 * b0.y + wu1 * b1.y);
  r.z = alpha * (wc0 * a0.z + wc1 * a1.z) + om * (wu0 * b0.z + wu1 * b1.z);
  r.w = alpha * (wc0 * a0.w + wc1 * a1.w) + om * (wu0 * b0.w + wu1 * b1.w);
  ((float4*)out)[i] = r;
}

extern "C" void kernel_launch(void* const* d_in, const int* in_sizes, int n_in,
                              void* d_out, int out_size, void* d_ws, size_t ws_size,
                              hipStream_t stream) {
  const float* x = (const float*)d_in[0];
  const float* Wq = (const float*)d_in[1];
  const float* Wk = (const float*)d_in[2];
  const float* Wv = (const float*)d_in[3];
  const float* falpha = (const float*)d_in[9];
  char* ws = (char*)d_ws;
  float* cosT = (float*)(ws);                       // 1 MB
  float* sinT = (float*)(ws + 1048576);             // 1 MB
  short* WT = (short*)(ws + 2097152);               // 768 KB  [384][1024] bf16
  short* Qb = (short*)(ws + 2883584);               // 4 MB    roped+scaled Q bf16
  short* Kb = (short*)(ws + 7077888);               // 1 MB    roped pooled K bf16
  short* VT = (short*)(ws + 8126464);               // 1 MB    pooled V^T bf16 [b][d][k]
  float* accC = (float*)(ws + 9175040);             // 16 MB   causal partials
  float* accU = (float*)(ws + 25952256);            // 16 MB   unmasked partials
  float2* mlC = (float2*)(ws + 42729472);           // 256 KB
  float2* mlU = (float2*)(ws + 42991616);           // 256 KB

  rope_kernel<<<1024, 256, 0, stream>>>(cosT, sinT);
  wtprep_kernel<<<1536, 256, 0, stream>>>(Wq, Wk, Wv, WT);
  gemm_fused<<<256, 256, 0, stream>>>(x, WT, cosT, sinT, Qb, Kb, VT);
  attn2_kernel<<<2048, 64, 0, stream>>>(Qb, Kb, VT, accC, mlC, accU, mlU);
  merge_kernel<<<2048, 256, 0, stream>>>(accC, mlC, accU, mlU, falpha, (float*)d_out);
}

// Round 3
// 80.865 us; speedup vs baseline: 1.9879x; 1.7342x over previous
//
#include <hip/hip_runtime.h>
#include <hip/hip_bf16.h>
#include <math.h>

// FluxHead: B=4, T=4096, D_MODEL=1024, HEAD_DIM=128, STRIDE=4, Tk=1024, CAUSAL
// Exact-math simplifications:
//  - spectral gate adds a per-(b,q) scalar to logits -> softmax-invariant -> skipped
//  - reverse branch == unmasked forward attention, output read at mirror row
//  - pooling commutes with K/V projection -> pooled in GEMM epilogue (lane-local)
//  - log2e/SCALE folded into Wq -> softmax in exp2 units

#define T_ 4096
#define TK_ 1024

typedef __attribute__((ext_vector_type(8))) short bf16x8;
typedef __attribute__((ext_vector_type(4))) float f32x4;
typedef __attribute__((ext_vector_type(4))) short s16x4;
typedef __attribute__((address_space(1))) unsigned int gas_u32;
typedef __attribute__((address_space(3))) unsigned int las_u32;

__device__ inline short f2bf(float f) {
  unsigned u = __builtin_bit_cast(unsigned, f);
  u = (u + 0x7FFFu + ((u >> 16) & 1u)) >> 16;
  return (short)u;
}
__device__ inline f32x4 mfma16(bf16x8 a, bf16x8 b, f32x4 c) {
  return __builtin_amdgcn_mfma_f32_16x16x32_bf16(a, b, c, 0, 0, 0);
}
__device__ inline void gll16(const void* g, void* l) {
  __builtin_amdgcn_global_load_lds((gas_u32*)g, (las_u32*)l, 16, 0, 0);
}
#define VMCNT(n) asm volatile("s_waitcnt vmcnt(" #n ")" ::: "memory")

// ---- rope table: cos/sin[t][d], t<4096, d<64 ----
__global__ __launch_bounds__(256) void rope_kernel(float* __restrict__ cosT,
                                                   float* __restrict__ sinT) {
  int i = blockIdx.x * 256 + threadIdx.x;  // 262144
  int t = i >> 6, d = i & 63;
  float theta = powf(10000.f, -(float)d * (1.f / 64.f));
  float fr = (float)t * theta;
  cosT[i] = cosf(fr);
  sinT[i] = sinf(fr);
}

// ---- WT prep, pre-swizzled for global_load_lds staging.
// Row order: [0..127]=Wq*scale, [128..191]=Wv hi, [192..319]=Wk, [320..383]=Wv lo
// Stored byte within each 128B k-block XOR'd by ((n&7)<<4).
__global__ __launch_bounds__(256) void wtprep_kernel(const float* __restrict__ Wq,
                                                     const float* __restrict__ Wk,
                                                     const float* __restrict__ Wv,
                                                     char* __restrict__ WT) {
  int i = blockIdx.x * 256 + threadIdx.x;  // 384*1024
  int n = i >> 10, k = i & 1023;
  float v;
  if (n < 128) v = Wq[(size_t)k * 128 + n] * 0.12751741656f;  // log2(e)/sqrt(128)
  else if (n < 192) v = Wv[(size_t)k * 128 + (n - 64)];
  else if (n < 320) v = Wk[(size_t)k * 128 + (n - 192)];
  else v = Wv[(size_t)k * 128 + (n - 320)];
  size_t off = (size_t)n * 2048 + (size_t)(k >> 6) * 128 + (((k & 63) * 2) ^ ((n & 7) << 4));
  *(short*)(WT + off) = f2bf(v);
}

// ---- fused projection GEMM: 64 rows x {Q|K|V} cols, K=1024
// W staged via global_load_lds (double-buffered), A (x) direct global w/ reg prefetch.
// Epilogue: Q roped; K pooled+roped -> swizzled Kswz; V pooled -> swizzled Vswz.
__global__ __launch_bounds__(256) void gemm_fused(const float* __restrict__ x,
                                                  const char* __restrict__ WT,
                                                  const float* __restrict__ cosT,
                                                  const float* __restrict__ sinT,
                                                  short* __restrict__ Qb,
                                                  char* __restrict__ Kswz,
                                                  char* __restrict__ Vswz) {
  __shared__ char Wl[2][49152];
  const int tid = threadIdx.x;
  const int w = tid >> 6, g = (tid >> 4) & 3, c = tid & 15;
  const int m0 = blockIdx.x * 64;
  const int mrow = m0 + (w & 1) * 32;
  const int nside = w >> 1;
  f32x4 acc[2][12];
#pragma unroll
  for (int mf = 0; mf < 2; mf++)
#pragma unroll
    for (int n = 0; n < 12; n++) acc[mf][n] = (f32x4){0.f, 0.f, 0.f, 0.f};
  float4 pa[8], pb[8];

  auto APF = [&](float4* p, int ki) {
#pragma unroll
    for (int mf = 0; mf < 2; mf++)
#pragma unroll
      for (int kc = 0; kc < 2; kc++)
#pragma unroll
        for (int hh = 0; hh < 2; hh++)
          p[mf * 4 + kc * 2 + hh] = *(const float4*)(
              x + ((size_t)(mrow + mf * 16 + c)) * 1024 + ki * 64 + kc * 32 + 8 * g + 4 * hh);
  };
  auto STAGE = [&](int ki, int buf) {
#pragma unroll
    for (int j = 0; j < 12; j++) {
      int chunk = j * 256 + tid;
      int row = chunk >> 3, inner = chunk & 7;
      gll16(WT + (size_t)row * 2048 + ki * 128 + inner * 16, &Wl[buf][chunk * 16]);
    }
  };
  auto COMPUTE = [&](const float4* p, int buf) {
    bf16x8 af[2][2];
#pragma unroll
    for (int mf = 0; mf < 2; mf++)
#pragma unroll
      for (int kc = 0; kc < 2; kc++) {
        float4 lo = p[mf * 4 + kc * 2], hi = p[mf * 4 + kc * 2 + 1];
        bf16x8 t = {f2bf(lo.x), f2bf(lo.y), f2bf(lo.z), f2bf(lo.w),
                    f2bf(hi.x), f2bf(hi.y), f2bf(hi.z), f2bf(hi.w)};
        af[mf][kc] = t;
      }
#pragma unroll
    for (int kc = 0; kc < 2; kc++)
#pragma unroll
      for (int n0 = 0; n0 < 12; n0++) {
        int row = nside * 192 + n0 * 16 + c;
        bf16x8 wf = *(const bf16x8*)(&Wl[buf][row * 128 + ((kc * 64 + 16 * g) ^ ((row & 7) << 4))]);
#pragma unroll
        for (int mf = 0; mf < 2; mf++) acc[mf][n0] = mfma16(af[mf][kc], wf, acc[mf][n0]);
      }
  };

  APF(pa, 0);
  STAGE(0, 0);
#pragma unroll 1
  for (int ki = 0; ki < 16; ki += 2) {
    STAGE(ki + 1, 1);
    APF(pb, ki + 1);
    VMCNT(20);
    __builtin_amdgcn_s_barrier();
    COMPUTE(pa, 0);
    __builtin_amdgcn_s_barrier();
    if (ki + 2 < 16) {
      STAGE(ki + 2, 0);
      APF(pa, ki + 2);
      VMCNT(20);
    } else {
      VMCNT(0);
    }
    __builtin_amdgcn_s_barrier();
    COMPUTE(pb, 1);
    __builtin_amdgcn_s_barrier();
  }

  if (nside == 0) {
    // Q (n0 0..3 lo / 4..7 hi) + V hi (n0 8..11)
#pragma unroll
    for (int mf = 0; mf < 2; mf++) {
#pragma unroll
      for (int r = 0; r < 4; r++) {
        int m = mrow + mf * 16 + 4 * g + r;
        int t = m & 4095;
#pragma unroll
        for (int n0 = 0; n0 < 4; n0++) {
          int dm = n0 * 16 + c;
          float co = cosT[t * 64 + dm], si = sinT[t * 64 + dm];
          float lo = acc[mf][n0][r], hi = acc[mf][n0 + 4][r];
          Qb[(size_t)m * 128 + dm] = f2bf(lo * co - hi * si);
          Qb[(size_t)m * 128 + dm + 64] = f2bf(hi * co + lo * si);
        }
      }
      int kp = ((mrow + mf * 16) >> 2) + g;
      int bb = kp >> 10, kpos = kp & 1023;
#pragma unroll
      for (int n0 = 8; n0 < 12; n0++) {
        float vp = 0.25f * (acc[mf][n0][0] + acc[mf][n0][1] + acc[mf][n0][2] + acc[mf][n0][3]);
        int dm = 64 + (n0 - 8) * 16 + c;
        size_t off = ((size_t)(bb * 16 + (kpos >> 6)) * 128 + dm) * 128 +
                     (((kpos & 63) * 2) ^ ((dm & 7) << 4));
        *(short*)(Vswz + off) = f2bf(vp);
      }
    }
  } else {
    // K (n0 0..3 lo / 4..7 hi) + V lo (n0 8..11)
#pragma unroll
    for (int mf = 0; mf < 2; mf++) {
      int kp = ((mrow + mf * 16) >> 2) + g;
      int bb = kp >> 10, kpos = kp & 1023;
      float ka[8];
#pragma unroll
      for (int j = 0; j < 8; j++)
        ka[j] = 0.25f * (acc[mf][j][0] + acc[mf][j][1] + acc[mf][j][2] + acc[mf][j][3]);
      size_t kbase = (size_t)kp * 256;
#pragma unroll
      for (int j = 0; j < 4; j++) {
        int dm = j * 16 + c;
        float co = cosT[kpos * 64 + dm], si = sinT[kpos * 64 + dm];
        float lo = ka[j], hi = ka[j + 4];
        *(short*)(Kswz + kbase + ((dm * 2) ^ ((kp & 7) << 4))) = f2bf(lo * co - hi * si);
        *(short*)(Kswz + kbase + (((dm + 64) * 2) ^ ((kp & 7) << 4))) = f2bf(hi * co + lo * si);
      }
#pragma unroll
      for (int n0 = 8; n0 < 12; n0++) {
        float vp = 0.25f * (acc[mf][n0][0] + acc[mf][n0][1] + acc[mf][n0][2] + acc[mf][n0][3]);
        int dm = (n0 - 8) * 16 + c;
        size_t off = ((size_t)(bb * 16 + (kpos >> 6)) * 128 + dm) * 128 +
                     (((kpos & 63) * 2) ^ ((dm & 7) << 4));
        *(short*)(Vswz + off) = f2bf(vp);
      }
    }
  }
}

// ---- fused two-branch flash attention, mirror-paired block ----
// 512 thr = 8 waves: waves 0-3 causal rows [q0b, q0b+64); waves 4-7 unmasked
// mirror rows; combine through LDS; swapped QK^T (lane-local softmax).
__global__ __launch_bounds__(512) void attn_kernel(const short* __restrict__ Qb,
                                                   const char* __restrict__ Kswz,
                                                   const char* __restrict__ Vswz,
                                                   const float* __restrict__ alphap,
                                                   float* __restrict__ out) {
  __shared__ char lds[2 * 16384 + 2 * 16384 + 8 * 2304];
  char* Kl = lds;
  char* Vl = lds + 32768;
  const int tid = threadIdx.x;
  const int w = tid >> 6, g = (tid >> 4) & 3, c = tid & 15;
  char* Pl = lds + 65536 + w * 2304;
  const int blk = blockIdx.x;
  const int b = blk >> 6, qc = blk & 63;
  const int q0b = qc * 64;
  const int tile_b = qc >> 2;
  const bool isC = (w < 4);
  const int qbase = isC ? (q0b + w * 16) : (4032 - q0b + (w - 4) * 16);
  const int myq = qbase + c;
  const int swc = (c & 7) << 4;

  bf16x8 qf[4];
  {
    const short* qr = Qb + ((size_t)b * T_ + myq) * 128;
#pragma unroll
    for (int kc = 0; kc < 4; kc++) qf[kc] = *(const bf16x8*)(qr + kc * 32 + 8 * g);
  }
  f32x4 acc[8];
#pragma unroll
  for (int n = 0; n < 8; n++) acc[n] = (f32x4){0.f, 0.f, 0.f, 0.f};
  float m = -1e30f, l = 0.f;

  const char* kbB = Kswz + (size_t)b * 262144;
  const char* vbB = Vswz + (size_t)b * 262144;

  // prologue: stage tile 0 -> buffer 0
  gll16(kbB + tid * 16, Kl + tid * 16);
  gll16(kbB + 8192 + tid * 16, Kl + 8192 + tid * 16);
  gll16(vbB + tid * 16, Vl + tid * 16);
  gll16(vbB + 8192 + tid * 16, Vl + 8192 + tid * 16);

#pragma unroll 1
  for (int tg = 0; tg < 16; tg++) {
    const int cur = (tg & 1) * 16384;
    const int nxt = 16384 - cur;
    if (tg < 15) {
      const char* kb = kbB + (size_t)(tg + 1) * 16384;
      const char* vb = vbB + (size_t)(tg + 1) * 16384;
      gll16(kb + tid * 16, Kl + nxt + tid * 16);
      gll16(kb + 8192 + tid * 16, Kl + nxt + 8192 + tid * 16);
      gll16(vb + tid * 16, Vl + nxt + tid * 16);
      gll16(vb + 8192 + tid * 16, Vl + nxt + 8192 + tid * 16);
      VMCNT(4);
    } else {
      VMCNT(0);
    }
    __builtin_amdgcn_s_barrier();

    if (!isC || tg <= tile_b) {
      // QK^T swapped: s[n][r] = S[key = tg*64 + 16n + 4g + r][q = myq]
      f32x4 s[4];
#pragma unroll
      for (int n = 0; n < 4; n++) s[n] = (f32x4){0.f, 0.f, 0.f, 0.f};
#pragma unroll
      for (int kc = 0; kc < 4; kc++) {
#pragma unroll
        for (int n = 0; n < 4; n++) {
          int row = 16 * n + c;
          bf16x8 kf = *(const bf16x8*)(Kl + cur + row * 256 + ((kc * 64 + 16 * g) ^ swc));
          s[n] = mfma16(kf, qf[kc], s[n]);
        }
      }
      if (isC && tg == tile_b) {  // boundary mask
        int klim = (myq >> 2) - tg * 64;
#pragma unroll
        for (int n = 0; n < 4; n++)
#pragma unroll
          for (int r = 0; r < 4; r++)
            if (16 * n + 4 * g + r > klim) s[n][r] = -3.0e38f;
      }
      // row max over 64 keys (16 lane-local + cross-g)
      float tm = fmaxf(fmaxf(fmaxf(s[0][0], s[0][1]), fmaxf(s[0][2], s[0][3])),
                       fmaxf(fmaxf(s[1][0], s[1][1]), fmaxf(s[1][2], s[1][3])));
      tm = fmaxf(tm, fmaxf(fmaxf(fmaxf(s[2][0], s[2][1]), fmaxf(s[2][2], s[2][3])),
                           fmaxf(fmaxf(s[3][0], s[3][1]), fmaxf(s[3][2], s[3][3]))));
      tm = fmaxf(tm, __shfl_xor(tm, 16));
      tm = fmaxf(tm, __shfl_xor(tm, 32));
      if (__any(tm > m + 8.f)) {  // defer-max
        float mn = fmaxf(m, tm);
        float sc = __builtin_amdgcn_exp2f(m - mn);
        m = mn;
        l *= sc;
        float s0 = __shfl(sc, 4 * g), s1 = __shfl(sc, 4 * g + 1);
        float s2 = __shfl(sc, 4 * g + 2), s3 = __shfl(sc, 4 * g + 3);
        f32x4 scv = {s0, s1, s2, s3};
#pragma unroll
        for (int n0 = 0; n0 < 8; n0++) acc[n0] *= scv;
      }
      float rsum = 0.f;
#pragma unroll
      for (int n = 0; n < 4; n++) {
        float p0 = __builtin_amdgcn_exp2f(s[n][0] - m);
        float p1 = __builtin_amdgcn_exp2f(s[n][1] - m);
        float p2 = __builtin_amdgcn_exp2f(s[n][2] - m);
        float p3 = __builtin_amdgcn_exp2f(s[n][3] - m);
        rsum += (p0 + p1) + (p2 + p3);
        s16x4 pk = {f2bf(p0), f2bf(p1), f2bf(p2), f2bf(p3)};
        *(s16x4*)(Pl + c * 144 + 32 * n + 8 * g) = pk;
      }
      rsum += __shfl_xor(rsum, 16);
      rsum += __shfl_xor(rsum, 32);
      l += rsum;
      bf16x8 pf0 = *(const bf16x8*)(Pl + c * 144 + 16 * g);
      bf16x8 pf1 = *(const bf16x8*)(Pl + c * 144 + 64 + 16 * g);
#pragma unroll
      for (int n0 = 0; n0 < 8; n0++) {
        const char* vrow = Vl + cur + (n0 * 16 + c) * 128;
        bf16x8 v0 = *(const bf16x8*)(vrow + ((16 * g) ^ swc));
        bf16x8 v1 = *(const bf16x8*)(vrow + ((64 + 16 * g) ^ swc));
        acc[n0] = mfma16(pf0, v0, acc[n0]);
        acc[n0] = mfma16(pf1, v1, acc[n0]);
      }
    }
    __builtin_amdgcn_s_barrier();
  }

  // epilogue: per-output-row 1/l, exchange U through LDS, combine, write
  float lr0 = __shfl(l, 4 * g), lr1 = __shfl(l, 4 * g + 1);
  float lr2 = __shfl(l, 4 * g + 2), lr3 = __shfl(l, 4 * g + 3);
  f32x4 linv = {1.f / lr0, 1.f / lr1, 1.f / lr2, 1.f / lr3};
  float* Ul = (float*)lds;  // [64][132] overlay (all K/V reads done)
  if (!isC) {
#pragma unroll
    for (int n0 = 0; n0 < 8; n0++)
#pragma unroll
      for (int r = 0; r < 4; r++) {
        int urow = 63 - (16 * (w - 4) + 4 * g + r);
        Ul[urow * 132 + n0 * 16 + c] = acc[n0][r] * linv[r];
      }
  }
  __syncthreads();
  if (isC) {
    float alpha = 1.f / (1.f + expf(-alphap[0]));
    float oma = 1.f - alpha;
#pragma unroll
    for (int n0 = 0; n0 < 8; n0++)
#pragma unroll
      for (int r = 0; r < 4; r++) {
        int q = q0b + 16 * w + 4 * g + r;
        float uvv = Ul[(16 * w + 4 * g + r) * 132 + n0 * 16 + c];
        out[((size_t)b * T_ + q) * 128 + n0 * 16 + c] = alpha * acc[n0][r] * linv[r] + oma * uvv;
      }
  }
}

extern "C" void kernel_launch(void* const* d_in, const int* in_sizes, int n_in,
                              void* d_out, int out_size, void* d_ws, size_t ws_size,
                              hipStream_t stream) {
  const float* x = (const float*)d_in[0];
  const float* Wq = (const float*)d_in[1];
  const float* Wk = (const float*)d_in[2];
  const float* Wv = (const float*)d_in[3];
  const float* falpha = (const float*)d_in[9];
  char* ws = (char*)d_ws;
  float* cosT = (float*)(ws);                  // 1 MB
  float* sinT = (float*)(ws + 1048576);        // 1 MB
  char* WT = ws + 2097152;                     // 768 KB  [384][1024] bf16, swizzled
  short* Qb = (short*)(ws + 2883584);          // 4 MB    roped+scaled Q bf16
  char* Kswz = ws + 7077888;                   // 1 MB    roped pooled K bf16, swizzled
  char* Vswz = ws + 8126464;                   // 1 MB    pooled V^T bf16, swizzled tiles

  rope_kernel<<<1024, 256, 0, stream>>>(cosT, sinT);
  wtprep_kernel<<<1536, 256, 0, stream>>>(Wq, Wk, Wv, WT);
  gemm_fused<<<256, 256, 0, stream>>>(x, WT, cosT, sinT, Qb, Kswz, Vswz);
  attn_kernel<<<256, 512, 0, stream>>>(Qb, Kswz, Vswz, falpha, (float*)d_out);
}